// Round 2
// baseline (369.756 us; speedup 1.0000x reference)
//
#include <hip/hip_runtime.h>
#include <hip/hip_bf16.h>

#define N_L 256
#define N_Q 65536
#define D_IN 384
#define D_CTX 192
#define HDIM 64
#define MAXA 6

__device__ __forceinline__ void fma4(float& acc, const float4& w, const float4& v) {
    acc = fmaf(w.x, v.x, acc);
    acc = fmaf(w.y, v.y, acc);
    acc = fmaf(w.z, v.z, acc);
    acc = fmaf(w.w, v.w, acc);
}

__device__ __forceinline__ float lgfact(int n) {
    // log(n!) for n in 0..6  (== gammaln(n+1))
    return (n <= 1) ? 0.0f :
           (n == 2) ? 0.6931471805599453f :
           (n == 3) ? 1.7917594692280550f :
           (n == 4) ? 3.1780538303479458f :
           (n == 5) ? 4.7874917427820460f :
                      6.5792512120101010f;
}

// ---------------- Kernel 1: VAE encode/reparam/decode + llm_emb + per-row loss partials ----
__global__ __launch_bounds__(64) void vae_kernel(
    const float* __restrict__ llms,
    const float* __restrict__ fc1_w, const float* __restrict__ fc1_b,
    const float* __restrict__ fc21_w, const float* __restrict__ fc21_b,
    const float* __restrict__ fc22_w, const float* __restrict__ fc22_b,
    const float* __restrict__ fc3_w, const float* __restrict__ fc3_b,
    const float* __restrict__ fc4_w, const float* __restrict__ fc4_b,
    const float* __restrict__ eps,
    float* __restrict__ emb_out, float* __restrict__ mse_row, float* __restrict__ kld_row)
{
    __shared__ __align__(16) float xs[D_IN];
    __shared__ __align__(16) float hs[HDIM];
    __shared__ __align__(16) float zs[HDIM];
    __shared__ __align__(16) float h2s[HDIM];
    const int r = blockIdx.x;
    const int j = threadIdx.x;

    for (int k = j; k < D_IN; k += 64) xs[k] = llms[r * D_IN + k];
    __syncthreads();

    // h = relu(fc1 x + b1), lane j computes h_j
    float acc = fc1_b[j];
    {
        const float4* wr = (const float4*)(fc1_w + (size_t)j * D_IN);
        const float4* xr = (const float4*)xs;
        #pragma unroll 8
        for (int k4 = 0; k4 < D_IN / 4; ++k4) { fma4(acc, wr[k4], xr[k4]); }
    }
    float h = fmaxf(acc, 0.0f);
    hs[j] = h;
    __syncthreads();

    // mu, log_var
    float mu = fc21_b[j], lv = fc22_b[j];
    {
        const float4* w1 = (const float4*)(fc21_w + (size_t)j * HDIM);
        const float4* w2 = (const float4*)(fc22_w + (size_t)j * HDIM);
        const float4* hr = (const float4*)hs;
        #pragma unroll
        for (int k4 = 0; k4 < HDIM / 4; ++k4) {
            float4 hh = hr[k4];
            fma4(mu, w1[k4], hh);
            fma4(lv, w2[k4], hh);
        }
    }
    float stdv = expf(0.5f * lv) * 0.1f;
    float z = fmaf(eps[r * HDIM + j], stdv, mu);

    // kld partial: 1 - LOG_VAR2 + lv - (mu^2 + exp(lv)) / VAR2
    float elv = expf(lv);
    float kt = (1.0f - (-4.60517018598809136f)) + lv - (mu * mu + elv) / 0.01f;
    float ks = kt;
    #pragma unroll
    for (int o = 32; o; o >>= 1) ks += __shfl_xor(ks, o);

    // llm_emb = z / max(||z||, 1e-12)
    float zsq = z * z;
    #pragma unroll
    for (int o = 32; o; o >>= 1) zsq += __shfl_xor(zsq, o);
    float nrm = fmaxf(sqrtf(zsq), 1e-12f);
    emb_out[r * HDIM + j] = z / nrm;
    zs[j] = z;
    __syncthreads();

    // h2 = relu(fc3 z + b3)
    float a3 = fc3_b[j];
    {
        const float4* w3 = (const float4*)(fc3_w + (size_t)j * HDIM);
        const float4* zr = (const float4*)zs;
        #pragma unroll
        for (int k4 = 0; k4 < HDIM / 4; ++k4) { fma4(a3, w3[k4], zr[k4]); }
    }
    float h2 = fmaxf(a3, 0.0f);
    h2s[j] = h2;
    __syncthreads();

    // x_hat and mse partial: 6 outputs per lane
    float ms = 0.0f;
    const float4* h2r = (const float4*)h2s;
    #pragma unroll
    for (int m = 0; m < 6; ++m) {
        int o = j + 64 * m;
        float a4 = fc4_b[o];
        const float4* w4 = (const float4*)(fc4_w + (size_t)o * HDIM);
        #pragma unroll
        for (int k4 = 0; k4 < HDIM / 4; ++k4) { fma4(a4, w4[k4], h2r[k4]); }
        float d = a4 - xs[o];
        ms = fmaf(d, d, ms);
    }
    #pragma unroll
    for (int o = 32; o; o >>= 1) ms += __shfl_xor(ms, o);
    if (j == 0) { mse_row[r] = ms; kld_row[r] = ks; }
}

// ---------------- Kernel 2: finalize vae_loss ----------------
__global__ __launch_bounds__(256) void loss_kernel(
    const float* __restrict__ mse_row, const float* __restrict__ kld_row, float* __restrict__ out_loss)
{
    __shared__ float sm[256], sk[256];
    int t = threadIdx.x;
    sm[t] = mse_row[t]; sk[t] = kld_row[t];
    __syncthreads();
    for (int s = 128; s > 0; s >>= 1) {
        if (t < s) { sm[t] += sm[t + s]; sk[t] += sk[t + s]; }
        __syncthreads();
    }
    if (t == 0) {
        float mse = sm[0] / 98304.0f;           // 256*384
        float kld = -0.5f * (sk[0] / 16384.0f); // 256*64
        out_loss[0] = mse + kld;
    }
}

// ---------------- Kernel 3: routing — ctx embed, scores, softmax, sampling, log_probs ------
__global__ __launch_bounds__(512) void route_kernel(
    const float* __restrict__ contexts, const float* __restrict__ ctx_w, const float* __restrict__ ctx_b,
    const float* __restrict__ emb, const int* __restrict__ agent_num, const float* __restrict__ rand_u,
    float* __restrict__ out_sel, float* __restrict__ out_lp)
{
    // ctx_w staged in LDS, rows padded to 196 floats (49 16B-granules -> conflict-free)
    __shared__ __align__(16) float wlds[HDIM * 196];
    __shared__ __align__(16) float elds[8][4 * HDIM];   // per-wave normalized ctx embeddings

    const int tid = threadIdx.x;
    const int lane = tid & 63;
    const int widx = tid >> 6;

    for (int f = tid; f < HDIM * D_CTX; f += 512) {
        int rr = f / D_CTX, cc = f - rr * D_CTX;
        wlds[rr * 196 + cc] = ctx_w[f];
    }
    __syncthreads();

    const float bj = ctx_b[lane];
    const float4* wrow = (const float4*)(wlds + lane * 196);
    float* ew = elds[widx];
    const int l0 = lane << 2;

    auto softmax4 = [&](float4& P) {
        float m = fmaxf(fmaxf(P.x, P.y), fmaxf(P.z, P.w));
        #pragma unroll
        for (int o = 32; o; o >>= 1) m = fmaxf(m, __shfl_xor(m, o));
        P.x = expf(P.x - m); P.y = expf(P.y - m); P.z = expf(P.z - m); P.w = expf(P.w - m);
        float s = P.x + P.y + P.z + P.w;
        #pragma unroll
        for (int o = 32; o; o >>= 1) s += __shfl_xor(s, o);
        float inv = 1.0f / s;
        P.x *= inv; P.y *= inv; P.z *= inv; P.w *= inv;
    };

    auto process_q = [&](float4& P, int qq, int Aq) -> float {
        // local inclusive cumsum over this lane's 4 probs
        float p0 = P.x, p1 = p0 + P.y, p2 = p1 + P.z, p3 = p2 + P.w;
        float t = p3;
        #pragma unroll
        for (int o = 1; o < 64; o <<= 1) { float v = __shfl_up(t, o); if (lane >= o) t += v; }
        float base = t - p3;
        float c0 = p0 + base, c1 = p1 + base, c2 = p2 + base, c3 = p3 + base;
        int n0 = 0, n1 = 0, n2 = 0, n3 = 0;
        for (int i = 0; i < Aq; ++i) {             // Aq wave-uniform
            float u = rand_u[i * N_Q + qq];
            int loc = (c0 <= u) + (c1 <= u) + (c2 <= u) + (c3 <= u);
            #pragma unroll
            for (int o = 32; o; o >>= 1) loc += __shfl_xor(loc, o);
            int sel = (loc >= N_L) ? 0 : loc;      // numpy argmax(all-False) == 0
            n0 += (sel == l0); n1 += (sel == l0 + 1); n2 += (sel == l0 + 2); n3 += (sel == l0 + 3);
        }
        // coalesced row write (covers every element; out was poisoned)
        float4 rowv = make_float4((float)n0, (float)n1, (float)n2, (float)n3);
        *(((float4*)(out_sel + (size_t)qq * N_L)) + lane) = rowv;
        // log-prob contribution: sum c*log(s) - log(c!)
        float term = 0.0f;
        if (n0) term += (float)n0 * logf(P.x) - lgfact(n0);
        if (n1) term += (float)n1 * logf(P.y) - lgfact(n1);
        if (n2) term += (float)n2 * logf(P.z) - lgfact(n2);
        if (n3) term += (float)n3 * logf(P.w) - lgfact(n3);
        #pragma unroll
        for (int o = 32; o; o >>= 1) term += __shfl_xor(term, o);
        return term;
    };

    const int nwaves = gridDim.x * 8;
    for (int g = blockIdx.x * 8 + widx; g < (N_Q / 4); g += nwaves) {
        const int q0 = __builtin_amdgcn_readfirstlane(g << 2);

        // ---- phase 1: e_j for 4 queries (lane j computes feature j) ----
        float e0 = bj, e1 = bj, e2 = bj, e3 = bj;
        const float4* cp = (const float4*)(contexts + (size_t)q0 * D_CTX);
        #pragma unroll 4
        for (int k4 = 0; k4 < D_CTX / 4; ++k4) {
            float4 w = wrow[k4];
            fma4(e0, w, cp[k4]);
            fma4(e1, w, cp[48 + k4]);
            fma4(e2, w, cp[96 + k4]);
            fma4(e3, w, cp[144 + k4]);
        }
        float s0 = e0 * e0, s1 = e1 * e1, s2 = e2 * e2, s3 = e3 * e3;
        #pragma unroll
        for (int o = 32; o; o >>= 1) {
            s0 += __shfl_xor(s0, o); s1 += __shfl_xor(s1, o);
            s2 += __shfl_xor(s2, o); s3 += __shfl_xor(s3, o);
        }
        e0 *= 1.0f / fmaxf(sqrtf(s0), 1e-12f);
        e1 *= 1.0f / fmaxf(sqrtf(s1), 1e-12f);
        e2 *= 1.0f / fmaxf(sqrtf(s2), 1e-12f);
        e3 *= 1.0f / fmaxf(sqrtf(s3), 1e-12f);
        ew[0 * HDIM + lane] = e0; ew[1 * HDIM + lane] = e1;
        ew[2 * HDIM + lane] = e2; ew[3 * HDIM + lane] = e3;   // same-wave write->read, program order

        // ---- phase 2: logits for this lane's 4 llms x 4 queries ----
        float4 A0 = {0,0,0,0}, A1 = {0,0,0,0}, A2 = {0,0,0,0}, A3 = {0,0,0,0};
        const float4* er = (const float4*)ew;
        const float4* embp = (const float4*)(emb + (size_t)l0 * HDIM);
        #pragma unroll 2
        for (int j4 = 0; j4 < HDIM / 4; ++j4) {
            float4 m0 = embp[j4], m1 = embp[16 + j4], m2 = embp[32 + j4], m3 = embp[48 + j4];
            float4 q0v = er[j4], q1v = er[16 + j4], q2v = er[32 + j4], q3v = er[48 + j4];
            fma4(A0.x, m0, q0v); fma4(A0.y, m1, q0v); fma4(A0.z, m2, q0v); fma4(A0.w, m3, q0v);
            fma4(A1.x, m0, q1v); fma4(A1.y, m1, q1v); fma4(A1.z, m2, q1v); fma4(A1.w, m3, q1v);
            fma4(A2.x, m0, q2v); fma4(A2.y, m1, q2v); fma4(A2.z, m2, q2v); fma4(A2.w, m3, q2v);
            fma4(A3.x, m0, q3v); fma4(A3.y, m1, q3v); fma4(A3.z, m2, q3v); fma4(A3.w, m3, q3v);
        }

        const int Aq0 = agent_num[q0 + 0];
        const int Aq1 = agent_num[q0 + 1];
        const int Aq2 = agent_num[q0 + 2];
        const int Aq3 = agent_num[q0 + 3];

        softmax4(A0); softmax4(A1); softmax4(A2); softmax4(A3);

        float r0 = process_q(A0, q0 + 0, Aq0);
        float r1 = process_q(A1, q0 + 1, Aq1);
        float r2 = process_q(A2, q0 + 2, Aq2);
        float r3 = process_q(A3, q0 + 3, Aq3);

        if (lane < 4) {
            float rr = (lane == 0) ? r0 : (lane == 1) ? r1 : (lane == 2) ? r2 : r3;
            int Aa   = (lane == 0) ? Aq0 : (lane == 1) ? Aq1 : (lane == 2) ? Aq2 : Aq3;
            out_lp[q0 + lane] = lgfact(Aa) + rr;
        }
    }
}

extern "C" void kernel_launch(void* const* d_in, const int* in_sizes, int n_in,
                              void* d_out, int out_size, void* d_ws, size_t ws_size,
                              hipStream_t stream) {
    const float* llms      = (const float*)d_in[0];
    const float* contexts  = (const float*)d_in[1];
    const int*   agent_i   = (const int*)  d_in[2];
    // d_in[3] agent_num_float unused (int version + table)
    const float* fc1_w  = (const float*)d_in[4];  const float* fc1_b  = (const float*)d_in[5];
    const float* fc21_w = (const float*)d_in[6];  const float* fc21_b = (const float*)d_in[7];
    const float* fc22_w = (const float*)d_in[8];  const float* fc22_b = (const float*)d_in[9];
    const float* fc3_w  = (const float*)d_in[10]; const float* fc3_b  = (const float*)d_in[11];
    const float* fc4_w  = (const float*)d_in[12]; const float* fc4_b  = (const float*)d_in[13];
    const float* ctx_w  = (const float*)d_in[14]; const float* ctx_b  = (const float*)d_in[15];
    const float* noise  = (const float*)d_in[16]; const float* rand_u = (const float*)d_in[17];

    float* out      = (float*)d_out;
    float* out_sel  = out;                          // [65536][256]
    float* out_lp   = out + (size_t)N_Q * N_L;      // [65536]
    float* out_loss = out_lp + N_Q;                 // [1]

    float* emb      = (float*)d_ws;                 // [256][64]
    float* mse_row  = emb + N_L * HDIM;             // [256]
    float* kld_row  = mse_row + N_L;                // [256]

    vae_kernel<<<N_L, 64, 0, stream>>>(llms, fc1_w, fc1_b, fc21_w, fc21_b, fc22_w, fc22_b,
                                       fc3_w, fc3_b, fc4_w, fc4_b, noise,
                                       emb, mse_row, kld_row);
    loss_kernel<<<1, 256, 0, stream>>>(mse_row, kld_row, out_loss);
    route_kernel<<<512, 512, 0, stream>>>(contexts, ctx_w, ctx_b, emb, agent_i, rand_u,
                                          out_sel, out_lp);
}

// Round 3
// 355.819 us; speedup vs baseline: 1.0392x; 1.0392x over previous
//
#include <hip/hip_runtime.h>
#include <hip/hip_bf16.h>

#define N_L 256
#define N_Q 65536
#define D_IN 384
#define D_CTX 192
#define HDIM 64
#define MAXA 6

__device__ __forceinline__ void fma4(float& acc, const float4& w, const float4& v) {
    acc = fmaf(w.x, v.x, acc);
    acc = fmaf(w.y, v.y, acc);
    acc = fmaf(w.z, v.z, acc);
    acc = fmaf(w.w, v.w, acc);
}

__device__ __forceinline__ float lgfact(int n) {
    // log(n!) for n in 0..6  (== gammaln(n+1))
    return (n <= 1) ? 0.0f :
           (n == 2) ? 0.6931471805599453f :
           (n == 3) ? 1.7917594692280550f :
           (n == 4) ? 3.1780538303479458f :
           (n == 5) ? 4.7874917427820460f :
                      6.5792512120101010f;
}

__device__ __forceinline__ float rfl_f(float x) {
    return __int_as_float(__builtin_amdgcn_readfirstlane(__float_as_int(x)));
}

// ---------------- Kernel 1: VAE encode/reparam/decode + llm_emb + per-row loss partials ----
__global__ __launch_bounds__(64) void vae_kernel(
    const float* __restrict__ llms,
    const float* __restrict__ fc1_w, const float* __restrict__ fc1_b,
    const float* __restrict__ fc21_w, const float* __restrict__ fc21_b,
    const float* __restrict__ fc22_w, const float* __restrict__ fc22_b,
    const float* __restrict__ fc3_w, const float* __restrict__ fc3_b,
    const float* __restrict__ fc4_w, const float* __restrict__ fc4_b,
    const float* __restrict__ eps,
    float* __restrict__ emb_out, float* __restrict__ mse_row, float* __restrict__ kld_row)
{
    __shared__ __align__(16) float xs[D_IN];
    __shared__ __align__(16) float hs[HDIM];
    __shared__ __align__(16) float zs[HDIM];
    __shared__ __align__(16) float h2s[HDIM];
    const int r = blockIdx.x;
    const int j = threadIdx.x;

    for (int k = j; k < D_IN; k += 64) xs[k] = llms[r * D_IN + k];
    __syncthreads();

    // h = relu(fc1 x + b1), lane j computes h_j
    float acc = fc1_b[j];
    {
        const float4* wr = (const float4*)(fc1_w + (size_t)j * D_IN);
        const float4* xr = (const float4*)xs;
        #pragma unroll 8
        for (int k4 = 0; k4 < D_IN / 4; ++k4) { fma4(acc, wr[k4], xr[k4]); }
    }
    float h = fmaxf(acc, 0.0f);
    hs[j] = h;
    __syncthreads();

    // mu, log_var
    float mu = fc21_b[j], lv = fc22_b[j];
    {
        const float4* w1 = (const float4*)(fc21_w + (size_t)j * HDIM);
        const float4* w2 = (const float4*)(fc22_w + (size_t)j * HDIM);
        const float4* hr = (const float4*)hs;
        #pragma unroll
        for (int k4 = 0; k4 < HDIM / 4; ++k4) {
            float4 hh = hr[k4];
            fma4(mu, w1[k4], hh);
            fma4(lv, w2[k4], hh);
        }
    }
    float stdv = expf(0.5f * lv) * 0.1f;
    float z = fmaf(eps[r * HDIM + j], stdv, mu);

    // kld partial: 1 - LOG_VAR2 + lv - (mu^2 + exp(lv)) / VAR2
    float elv = expf(lv);
    float kt = (1.0f - (-4.60517018598809136f)) + lv - (mu * mu + elv) / 0.01f;
    float ks = kt;
    #pragma unroll
    for (int o = 32; o; o >>= 1) ks += __shfl_xor(ks, o);

    // llm_emb = z / max(||z||, 1e-12)
    float zsq = z * z;
    #pragma unroll
    for (int o = 32; o; o >>= 1) zsq += __shfl_xor(zsq, o);
    float nrm = fmaxf(sqrtf(zsq), 1e-12f);
    emb_out[r * HDIM + j] = z / nrm;
    zs[j] = z;
    __syncthreads();

    // h2 = relu(fc3 z + b3)
    float a3 = fc3_b[j];
    {
        const float4* w3 = (const float4*)(fc3_w + (size_t)j * HDIM);
        const float4* zr = (const float4*)zs;
        #pragma unroll
        for (int k4 = 0; k4 < HDIM / 4; ++k4) { fma4(a3, w3[k4], zr[k4]); }
    }
    float h2 = fmaxf(a3, 0.0f);
    h2s[j] = h2;
    __syncthreads();

    // x_hat and mse partial: 6 outputs per lane
    float ms = 0.0f;
    const float4* h2r = (const float4*)h2s;
    #pragma unroll
    for (int m = 0; m < 6; ++m) {
        int o = j + 64 * m;
        float a4 = fc4_b[o];
        const float4* w4 = (const float4*)(fc4_w + (size_t)o * HDIM);
        #pragma unroll
        for (int k4 = 0; k4 < HDIM / 4; ++k4) { fma4(a4, w4[k4], h2r[k4]); }
        float d = a4 - xs[o];
        ms = fmaf(d, d, ms);
    }
    #pragma unroll
    for (int o = 32; o; o >>= 1) ms += __shfl_xor(ms, o);
    if (j == 0) { mse_row[r] = ms; kld_row[r] = ks; }
}

// ---------------- Kernel 2: finalize vae_loss ----------------
__global__ __launch_bounds__(256) void loss_kernel(
    const float* __restrict__ mse_row, const float* __restrict__ kld_row, float* __restrict__ out_loss)
{
    __shared__ float sm[256], sk[256];
    int t = threadIdx.x;
    sm[t] = mse_row[t]; sk[t] = kld_row[t];
    __syncthreads();
    for (int s = 128; s > 0; s >>= 1) {
        if (t < s) { sm[t] += sm[t + s]; sk[t] += sk[t + s]; }
        __syncthreads();
    }
    if (t == 0) {
        float mse = sm[0] / 98304.0f;           // 256*384
        float kld = -0.5f * (sk[0] / 16384.0f); // 256*64
        out_loss[0] = mse + kld;
    }
}

// ---------------- Kernel 3: ctx embedding (phase 1) -> first 64 floats of each out row ----
// e vectors parked in the query's OWN output row (overwritten later by the same wave in
// route_kernel after it has consumed them — disjoint per wave, no races, no ws needed).
__global__ __launch_bounds__(512) void ctx_kernel(
    const float* __restrict__ contexts, const float* __restrict__ ctx_w, const float* __restrict__ ctx_b,
    float* __restrict__ out_sel)
{
    __shared__ __align__(16) float wlds[HDIM * 196];  // rows padded to 196 floats

    const int tid = threadIdx.x;
    const int lane = tid & 63;
    const int widx = tid >> 6;

    for (int f = tid; f < HDIM * D_CTX; f += 512) {
        int rr = f / D_CTX, cc = f - rr * D_CTX;
        wlds[rr * 196 + cc] = ctx_w[f];
    }
    __syncthreads();

    const float bj = ctx_b[lane];
    const float4* wrow = (const float4*)(wlds + lane * 196);

    const int g = blockIdx.x * 8 + widx;               // [0, 16384)
    const int q0 = __builtin_amdgcn_readfirstlane(g << 2);

    float e0 = bj, e1 = bj, e2 = bj, e3 = bj;
    const float4* cp = (const float4*)(contexts + (size_t)q0 * D_CTX);
    #pragma unroll 4
    for (int k4 = 0; k4 < D_CTX / 4; ++k4) {
        float4 w = wrow[k4];
        fma4(e0, w, cp[k4]);
        fma4(e1, w, cp[48 + k4]);
        fma4(e2, w, cp[96 + k4]);
        fma4(e3, w, cp[144 + k4]);
    }
    float s0 = e0 * e0, s1 = e1 * e1, s2 = e2 * e2, s3 = e3 * e3;
    #pragma unroll
    for (int o = 32; o; o >>= 1) {
        s0 += __shfl_xor(s0, o); s1 += __shfl_xor(s1, o);
        s2 += __shfl_xor(s2, o); s3 += __shfl_xor(s3, o);
    }
    e0 *= 1.0f / fmaxf(sqrtf(s0), 1e-12f);
    e1 *= 1.0f / fmaxf(sqrtf(s1), 1e-12f);
    e2 *= 1.0f / fmaxf(sqrtf(s2), 1e-12f);
    e3 *= 1.0f / fmaxf(sqrtf(s3), 1e-12f);

    out_sel[(size_t)(q0 + 0) * N_L + lane] = e0;
    out_sel[(size_t)(q0 + 1) * N_L + lane] = e1;
    out_sel[(size_t)(q0 + 2) * N_L + lane] = e2;
    out_sel[(size_t)(q0 + 3) * N_L + lane] = e3;
}

// ---------------- Kernel 4: routing — scores, softmax, sampling, log_probs ------
__global__ __launch_bounds__(256) void route_kernel(
    const float* __restrict__ emb, const int* __restrict__ agent_num, const float* __restrict__ rand_u,
    float* __restrict__ out_sel, float* __restrict__ out_lp)
{
    __shared__ __align__(16) float elds[4][4 * HDIM];   // per-wave e vectors, 4 KB total

    const int tid = threadIdx.x;
    const int lane = tid & 63;
    const int widx = tid >> 6;
    const int l0 = lane << 2;

    const int g = blockIdx.x * 4 + widx;                // [0, 16384)
    const int q0 = __builtin_amdgcn_readfirstlane(g << 2);
    float* ew = elds[widx];

    // ---- stage e vectors (parked in out rows by ctx_kernel); coalesced 256B loads ----
    #pragma unroll
    for (int qi = 0; qi < 4; ++qi)
        ew[qi * HDIM + lane] = out_sel[(size_t)(q0 + qi) * N_L + lane];

    // ---- preload agent counts + all 6x4 uniforms (scalarized) ----
    int Aq[4];
    #pragma unroll
    for (int qi = 0; qi < 4; ++qi)
        Aq[qi] = __builtin_amdgcn_readfirstlane(agent_num[q0 + qi]);
    float uu[MAXA][4];
    #pragma unroll
    for (int i = 0; i < MAXA; ++i)
        #pragma unroll
        for (int qi = 0; qi < 4; ++qi)
            uu[i][qi] = rfl_f(rand_u[i * N_Q + q0 + qi]);

    // ---- logits: lane's 4 llms x 4 queries ----
    float4 A0 = {0,0,0,0}, A1 = {0,0,0,0}, A2 = {0,0,0,0}, A3 = {0,0,0,0};
    const float4* er = (const float4*)ew;
    const float4* embp = (const float4*)(emb + (size_t)l0 * HDIM);
    #pragma unroll 2
    for (int j4 = 0; j4 < HDIM / 4; ++j4) {
        float4 m0 = embp[j4], m1 = embp[16 + j4], m2 = embp[32 + j4], m3 = embp[48 + j4];
        float4 q0v = er[j4], q1v = er[16 + j4], q2v = er[32 + j4], q3v = er[48 + j4];
        fma4(A0.x, m0, q0v); fma4(A0.y, m1, q0v); fma4(A0.z, m2, q0v); fma4(A0.w, m3, q0v);
        fma4(A1.x, m0, q1v); fma4(A1.y, m1, q1v); fma4(A1.z, m2, q1v); fma4(A1.w, m3, q1v);
        fma4(A2.x, m0, q2v); fma4(A2.y, m1, q2v); fma4(A2.z, m2, q2v); fma4(A2.w, m3, q2v);
        fma4(A3.x, m0, q3v); fma4(A3.y, m1, q3v); fma4(A3.z, m2, q3v); fma4(A3.w, m3, q3v);
    }
    float4 P[4] = {A0, A1, A2, A3};

    // ---- softmax, 4 queries interleaved (per-query op order identical to prior round) ----
    {
        float m[4], s[4];
        #pragma unroll
        for (int k = 0; k < 4; ++k) m[k] = fmaxf(fmaxf(P[k].x, P[k].y), fmaxf(P[k].z, P[k].w));
        #pragma unroll
        for (int o = 32; o; o >>= 1)
            #pragma unroll
            for (int k = 0; k < 4; ++k) m[k] = fmaxf(m[k], __shfl_xor(m[k], o));
        #pragma unroll
        for (int k = 0; k < 4; ++k) {
            P[k].x = expf(P[k].x - m[k]); P[k].y = expf(P[k].y - m[k]);
            P[k].z = expf(P[k].z - m[k]); P[k].w = expf(P[k].w - m[k]);
            s[k] = P[k].x + P[k].y + P[k].z + P[k].w;
        }
        #pragma unroll
        for (int o = 32; o; o >>= 1)
            #pragma unroll
            for (int k = 0; k < 4; ++k) s[k] += __shfl_xor(s[k], o);
        #pragma unroll
        for (int k = 0; k < 4; ++k) {
            float inv = 1.0f / s[k];
            P[k].x *= inv; P[k].y *= inv; P[k].z *= inv; P[k].w *= inv;
        }
    }

    // ---- inclusive cumsum, 4 queries interleaved (same per-query scan as before) ----
    float c0[4], c1[4], c2[4], c3[4];
    {
        float p3[4], t[4];
        #pragma unroll
        for (int k = 0; k < 4; ++k) {
            c0[k] = P[k].x; c1[k] = c0[k] + P[k].y; c2[k] = c1[k] + P[k].z; p3[k] = c2[k] + P[k].w;
            t[k] = p3[k];
        }
        #pragma unroll
        for (int o = 1; o < 64; o <<= 1)
            #pragma unroll
            for (int k = 0; k < 4; ++k) { float v = __shfl_up(t[k], o); if (lane >= o) t[k] += v; }
        #pragma unroll
        for (int k = 0; k < 4; ++k) {
            float base = t[k] - p3[k];
            c0[k] += base; c1[k] += base; c2[k] += base; c3[k] = p3[k] + base;
        }
    }

    // ---- sampling: ballot+popcount (exact integer count, no shfl chain) ----
    int n0[4] = {0,0,0,0}, n1[4] = {0,0,0,0}, n2[4] = {0,0,0,0}, n3[4] = {0,0,0,0};
    #pragma unroll
    for (int i = 0; i < MAXA; ++i) {
        #pragma unroll
        for (int k = 0; k < 4; ++k) {
            if (i < Aq[k]) {                       // wave-uniform scalar branch
                float u = uu[i][k];
                unsigned long long b0 = __ballot(c0[k] <= u);
                unsigned long long b1 = __ballot(c1[k] <= u);
                unsigned long long b2 = __ballot(c2[k] <= u);
                unsigned long long b3 = __ballot(c3[k] <= u);
                int loc = __popcll(b0) + __popcll(b1) + __popcll(b2) + __popcll(b3);
                int sel = (loc >= N_L) ? 0 : loc;  // numpy argmax(all-False) == 0
                n0[k] += (sel == l0); n1[k] += (sel == l0 + 1);
                n2[k] += (sel == l0 + 2); n3[k] += (sel == l0 + 3);
            }
        }
    }

    // ---- row stores + log-prob terms (same per-query arithmetic/order as before) ----
    float term[4];
    #pragma unroll
    for (int k = 0; k < 4; ++k) {
        float4 rowv = make_float4((float)n0[k], (float)n1[k], (float)n2[k], (float)n3[k]);
        *(((float4*)(out_sel + (size_t)(q0 + k) * N_L)) + lane) = rowv;
        float tm = 0.0f;
        if (n0[k]) tm += (float)n0[k] * logf(P[k].x) - lgfact(n0[k]);
        if (n1[k]) tm += (float)n1[k] * logf(P[k].y) - lgfact(n1[k]);
        if (n2[k]) tm += (float)n2[k] * logf(P[k].z) - lgfact(n2[k]);
        if (n3[k]) tm += (float)n3[k] * logf(P[k].w) - lgfact(n3[k]);
        term[k] = tm;
    }
    #pragma unroll
    for (int o = 32; o; o >>= 1)
        #pragma unroll
        for (int k = 0; k < 4; ++k) term[k] += __shfl_xor(term[k], o);

    if (lane < 4) {
        float rr = (lane == 0) ? term[0] : (lane == 1) ? term[1] : (lane == 2) ? term[2] : term[3];
        int Aa   = (lane == 0) ? Aq[0]  : (lane == 1) ? Aq[1]  : (lane == 2) ? Aq[2]  : Aq[3];
        out_lp[q0 + lane] = lgfact(Aa) + rr;
    }
}

extern "C" void kernel_launch(void* const* d_in, const int* in_sizes, int n_in,
                              void* d_out, int out_size, void* d_ws, size_t ws_size,
                              hipStream_t stream) {
    const float* llms      = (const float*)d_in[0];
    const float* contexts  = (const float*)d_in[1];
    const int*   agent_i   = (const int*)  d_in[2];
    // d_in[3] agent_num_float unused (int version + table)
    const float* fc1_w  = (const float*)d_in[4];  const float* fc1_b  = (const float*)d_in[5];
    const float* fc21_w = (const float*)d_in[6];  const float* fc21_b = (const float*)d_in[7];
    const float* fc22_w = (const float*)d_in[8];  const float* fc22_b = (const float*)d_in[9];
    const float* fc3_w  = (const float*)d_in[10]; const float* fc3_b  = (const float*)d_in[11];
    const float* fc4_w  = (const float*)d_in[12]; const float* fc4_b  = (const float*)d_in[13];
    const float* ctx_w  = (const float*)d_in[14]; const float* ctx_b  = (const float*)d_in[15];
    const float* noise  = (const float*)d_in[16]; const float* rand_u = (const float*)d_in[17];

    float* out      = (float*)d_out;
    float* out_sel  = out;                          // [65536][256]
    float* out_lp   = out + (size_t)N_Q * N_L;      // [65536]
    float* out_loss = out_lp + N_Q;                 // [1]

    float* emb      = (float*)d_ws;                 // [256][64]
    float* mse_row  = emb + N_L * HDIM;             // [256]
    float* kld_row  = mse_row + N_L;                // [256]

    ctx_kernel<<<2048, 512, 0, stream>>>(contexts, ctx_w, ctx_b, out_sel);
    vae_kernel<<<N_L, 64, 0, stream>>>(llms, fc1_w, fc1_b, fc21_w, fc21_b, fc22_w, fc22_b,
                                       fc3_w, fc3_b, fc4_w, fc4_b, noise,
                                       emb, mse_row, kld_row);
    loss_kernel<<<1, 256, 0, stream>>>(mse_row, kld_row, out_loss);
    route_kernel<<<4096, 256, 0, stream>>>(emb, agent_i, rand_u, out_sel, out_lp);
}

// Round 4
// 278.363 us; speedup vs baseline: 1.3283x; 1.2783x over previous
//
#include <hip/hip_runtime.h>
#include <hip/hip_bf16.h>

#define N_L 256
#define N_Q 65536
#define D_IN 384
#define D_CTX 192
#define HDIM 64
#define MAXA 6

__device__ __forceinline__ void fma4(float& acc, const float4& w, const float4& v) {
    acc = fmaf(w.x, v.x, acc);
    acc = fmaf(w.y, v.y, acc);
    acc = fmaf(w.z, v.z, acc);
    acc = fmaf(w.w, v.w, acc);
}

__device__ __forceinline__ float lgfact(int n) {
    // log(n!) for n in 0..6  (== gammaln(n+1))
    return (n <= 1) ? 0.0f :
           (n == 2) ? 0.6931471805599453f :
           (n == 3) ? 1.7917594692280550f :
           (n == 4) ? 3.1780538303479458f :
           (n == 5) ? 4.7874917427820460f :
                      6.5792512120101010f;
}

__device__ __forceinline__ float rfl_f(float x) {
    return __int_as_float(__builtin_amdgcn_readfirstlane(__float_as_int(x)));
}

// ---------------- Kernel 1: VAE encode/reparam/decode + llm_emb + per-row loss partials ----
__global__ __launch_bounds__(64) void vae_kernel(
    const float* __restrict__ llms,
    const float* __restrict__ fc1_w, const float* __restrict__ fc1_b,
    const float* __restrict__ fc21_w, const float* __restrict__ fc21_b,
    const float* __restrict__ fc22_w, const float* __restrict__ fc22_b,
    const float* __restrict__ fc3_w, const float* __restrict__ fc3_b,
    const float* __restrict__ fc4_w, const float* __restrict__ fc4_b,
    const float* __restrict__ eps,
    float* __restrict__ emb_out, float* __restrict__ mse_row, float* __restrict__ kld_row)
{
    __shared__ __align__(16) float xs[D_IN];
    __shared__ __align__(16) float hs[HDIM];
    __shared__ __align__(16) float zs[HDIM];
    __shared__ __align__(16) float h2s[HDIM];
    const int r = blockIdx.x;
    const int j = threadIdx.x;

    for (int k = j; k < D_IN; k += 64) xs[k] = llms[r * D_IN + k];
    __syncthreads();

    float acc = fc1_b[j];
    {
        const float4* wr = (const float4*)(fc1_w + (size_t)j * D_IN);
        const float4* xr = (const float4*)xs;
        #pragma unroll 8
        for (int k4 = 0; k4 < D_IN / 4; ++k4) { fma4(acc, wr[k4], xr[k4]); }
    }
    float h = fmaxf(acc, 0.0f);
    hs[j] = h;
    __syncthreads();

    float mu = fc21_b[j], lv = fc22_b[j];
    {
        const float4* w1 = (const float4*)(fc21_w + (size_t)j * HDIM);
        const float4* w2 = (const float4*)(fc22_w + (size_t)j * HDIM);
        const float4* hr = (const float4*)hs;
        #pragma unroll
        for (int k4 = 0; k4 < HDIM / 4; ++k4) {
            float4 hh = hr[k4];
            fma4(mu, w1[k4], hh);
            fma4(lv, w2[k4], hh);
        }
    }
    float stdv = expf(0.5f * lv) * 0.1f;
    float z = fmaf(eps[r * HDIM + j], stdv, mu);

    float elv = expf(lv);
    float kt = (1.0f - (-4.60517018598809136f)) + lv - (mu * mu + elv) / 0.01f;
    float ks = kt;
    #pragma unroll
    for (int o = 32; o; o >>= 1) ks += __shfl_xor(ks, o);

    float zsq = z * z;
    #pragma unroll
    for (int o = 32; o; o >>= 1) zsq += __shfl_xor(zsq, o);
    float nrm = fmaxf(sqrtf(zsq), 1e-12f);
    emb_out[r * HDIM + j] = z / nrm;
    zs[j] = z;
    __syncthreads();

    float a3 = fc3_b[j];
    {
        const float4* w3 = (const float4*)(fc3_w + (size_t)j * HDIM);
        const float4* zr = (const float4*)zs;
        #pragma unroll
        for (int k4 = 0; k4 < HDIM / 4; ++k4) { fma4(a3, w3[k4], zr[k4]); }
    }
    float h2 = fmaxf(a3, 0.0f);
    h2s[j] = h2;
    __syncthreads();

    float ms = 0.0f;
    const float4* h2r = (const float4*)h2s;
    #pragma unroll
    for (int m = 0; m < 6; ++m) {
        int o = j + 64 * m;
        float a4 = fc4_b[o];
        const float4* w4 = (const float4*)(fc4_w + (size_t)o * HDIM);
        #pragma unroll
        for (int k4 = 0; k4 < HDIM / 4; ++k4) { fma4(a4, w4[k4], h2r[k4]); }
        float d = a4 - xs[o];
        ms = fmaf(d, d, ms);
    }
    #pragma unroll
    for (int o = 32; o; o >>= 1) ms += __shfl_xor(ms, o);
    if (j == 0) { mse_row[r] = ms; kld_row[r] = ks; }
}

// ---------------- Kernel 2: finalize vae_loss ----------------
__global__ __launch_bounds__(256) void loss_kernel(
    const float* __restrict__ mse_row, const float* __restrict__ kld_row, float* __restrict__ out_loss)
{
    __shared__ float sm[256], sk[256];
    int t = threadIdx.x;
    sm[t] = mse_row[t]; sk[t] = kld_row[t];
    __syncthreads();
    for (int s = 128; s > 0; s >>= 1) {
        if (t < s) { sm[t] += sm[t + s]; sk[t] += sk[t + s]; }
        __syncthreads();
    }
    if (t == 0) {
        float mse = sm[0] / 98304.0f;           // 256*384
        float kld = -0.5f * (sk[0] / 16384.0f); // 256*64
        out_loss[0] = mse + kld;
    }
}

// ---------------- Kernel 3: ctx embedding -> first 64 floats of each out row ----
__global__ __launch_bounds__(512) void ctx_kernel(
    const float* __restrict__ contexts, const float* __restrict__ ctx_w, const float* __restrict__ ctx_b,
    float* __restrict__ out_sel)
{
    __shared__ __align__(16) float wlds[HDIM * 196];  // rows padded to 196 floats

    const int tid = threadIdx.x;
    const int lane = tid & 63;
    const int widx = tid >> 6;

    for (int f = tid; f < HDIM * D_CTX; f += 512) {
        int rr = f / D_CTX, cc = f - rr * D_CTX;
        wlds[rr * 196 + cc] = ctx_w[f];
    }
    __syncthreads();

    const float bj = ctx_b[lane];
    const float4* wrow = (const float4*)(wlds + lane * 196);

    const int g = blockIdx.x * 8 + widx;               // [0, 16384)
    const int q0 = __builtin_amdgcn_readfirstlane(g << 2);

    float e0 = bj, e1 = bj, e2 = bj, e3 = bj;
    const float4* cp = (const float4*)(contexts + (size_t)q0 * D_CTX);
    #pragma unroll 4
    for (int k4 = 0; k4 < D_CTX / 4; ++k4) {
        float4 w = wrow[k4];
        fma4(e0, w, cp[k4]);
        fma4(e1, w, cp[48 + k4]);
        fma4(e2, w, cp[96 + k4]);
        fma4(e3, w, cp[144 + k4]);
    }
    float s0 = e0 * e0, s1 = e1 * e1, s2 = e2 * e2, s3 = e3 * e3;
    #pragma unroll
    for (int o = 32; o; o >>= 1) {
        s0 += __shfl_xor(s0, o); s1 += __shfl_xor(s1, o);
        s2 += __shfl_xor(s2, o); s3 += __shfl_xor(s3, o);
    }
    e0 *= 1.0f / fmaxf(sqrtf(s0), 1e-12f);
    e1 *= 1.0f / fmaxf(sqrtf(s1), 1e-12f);
    e2 *= 1.0f / fmaxf(sqrtf(s2), 1e-12f);
    e3 *= 1.0f / fmaxf(sqrtf(s3), 1e-12f);

    out_sel[(size_t)(q0 + 0) * N_L + lane] = e0;
    out_sel[(size_t)(q0 + 1) * N_L + lane] = e1;
    out_sel[(size_t)(q0 + 2) * N_L + lane] = e2;
    out_sel[(size_t)(q0 + 3) * N_L + lane] = e3;
}

// ---------------- Kernel 4: routing — scores, softmax, sampling, log_probs (Q=8/wave) ------
__global__ __launch_bounds__(256) void route_kernel(
    const float* __restrict__ emb, const int* __restrict__ agent_num, const float* __restrict__ rand_u,
    float* __restrict__ out_sel, float* __restrict__ out_lp)
{
    const int tid = threadIdx.x;
    const int lane = tid & 63;
    const int widx = tid >> 6;
    const int l0 = lane << 2;

    const int g = blockIdx.x * 4 + widx;                // wave id [0, 8192)
    const int q0 = __builtin_amdgcn_readfirstlane(g << 3);

    // ---- logits: lane's 4 llms x 8 queries; e read as uniform broadcast loads ----
    float4 P[8];
    #pragma unroll
    for (int q = 0; q < 8; ++q) P[q] = make_float4(0.f, 0.f, 0.f, 0.f);

    const float4* embp = (const float4*)(emb + (size_t)l0 * HDIM);
    #pragma unroll
    for (int c = 0; c < 8; ++c) {                       // k-chunks of 8 floats (2 float4)
        float4 m0[2], m1[2], m2[2], m3[2];
        #pragma unroll
        for (int j = 0; j < 2; ++j) {
            int j4 = c * 2 + j;
            m0[j] = embp[j4]; m1[j] = embp[16 + j4]; m2[j] = embp[32 + j4]; m3[j] = embp[48 + j4];
        }
        #pragma unroll
        for (int q = 0; q < 8; ++q) {
            const float4* ep = (const float4*)(out_sel + (size_t)(q0 + q) * N_L);
            #pragma unroll
            for (int j = 0; j < 2; ++j) {
                float4 ev = ep[c * 2 + j];              // wave-uniform address -> broadcast
                fma4(P[q].x, m0[j], ev);
                fma4(P[q].y, m1[j], ev);
                fma4(P[q].z, m2[j], ev);
                fma4(P[q].w, m3[j], ev);
            }
        }
    }

    // ---- agent counts + uniforms (scalarized; lifetime after logits) ----
    int Aq[8];
    #pragma unroll
    for (int q = 0; q < 8; ++q)
        Aq[q] = __builtin_amdgcn_readfirstlane(agent_num[q0 + q]);
    float uu[MAXA][8];
    #pragma unroll
    for (int i = 0; i < MAXA; ++i)
        #pragma unroll
        for (int q = 0; q < 8; ++q)
            uu[i][q] = rfl_f(rand_u[i * N_Q + q0 + q]);

    // ---- softmax, 8 queries interleaved (per-query op order unchanged) ----
    {
        float m[8], s[8];
        #pragma unroll
        for (int k = 0; k < 8; ++k) m[k] = fmaxf(fmaxf(P[k].x, P[k].y), fmaxf(P[k].z, P[k].w));
        #pragma unroll
        for (int o = 32; o; o >>= 1)
            #pragma unroll
            for (int k = 0; k < 8; ++k) m[k] = fmaxf(m[k], __shfl_xor(m[k], o));
        #pragma unroll
        for (int k = 0; k < 8; ++k) {
            P[k].x = expf(P[k].x - m[k]); P[k].y = expf(P[k].y - m[k]);
            P[k].z = expf(P[k].z - m[k]); P[k].w = expf(P[k].w - m[k]);
            s[k] = P[k].x + P[k].y + P[k].z + P[k].w;
        }
        #pragma unroll
        for (int o = 32; o; o >>= 1)
            #pragma unroll
            for (int k = 0; k < 8; ++k) s[k] += __shfl_xor(s[k], o);
        #pragma unroll
        for (int k = 0; k < 8; ++k) {
            float inv = 1.0f / s[k];
            P[k].x *= inv; P[k].y *= inv; P[k].z *= inv; P[k].w *= inv;
        }
    }

    // ---- inclusive cumsum, 8 queries interleaved (same per-query scan) ----
    float c0[8], c1[8], c2[8], c3[8];
    {
        float p3[8], t[8];
        #pragma unroll
        for (int k = 0; k < 8; ++k) {
            c0[k] = P[k].x; c1[k] = c0[k] + P[k].y; c2[k] = c1[k] + P[k].z; p3[k] = c2[k] + P[k].w;
            t[k] = p3[k];
        }
        #pragma unroll
        for (int o = 1; o < 64; o <<= 1)
            #pragma unroll
            for (int k = 0; k < 8; ++k) { float v = __shfl_up(t[k], o); if (lane >= o) t[k] += v; }
        #pragma unroll
        for (int k = 0; k < 8; ++k) {
            float base = t[k] - p3[k];
            c0[k] += base; c1[k] += base; c2[k] += base; c3[k] = p3[k] + base;
        }
    }

    // ---- sampling: ballot+popcount; counts nibble-packed (max 6 < 16) ----
    unsigned nib[8] = {0, 0, 0, 0, 0, 0, 0, 0};
    #pragma unroll
    for (int i = 0; i < MAXA; ++i) {
        #pragma unroll
        for (int k = 0; k < 8; ++k) {
            if (i < Aq[k]) {                       // wave-uniform scalar branch
                float u = uu[i][k];
                unsigned long long b0 = __ballot(c0[k] <= u);
                unsigned long long b1 = __ballot(c1[k] <= u);
                unsigned long long b2 = __ballot(c2[k] <= u);
                unsigned long long b3 = __ballot(c3[k] <= u);
                int loc = __popcll(b0) + __popcll(b1) + __popcll(b2) + __popcll(b3);
                int sel = (loc >= N_L) ? 0 : loc;  // numpy argmax(all-False) == 0
                unsigned d = (unsigned)(sel - l0);
                if (d < 4u) nib[k] += 1u << (4 * d);
            }
        }
    }

    // ---- row stores + log-prob terms (same per-query arithmetic/order) ----
    float term[8];
    #pragma unroll
    for (int k = 0; k < 8; ++k) {
        int n0 = nib[k] & 15, n1 = (nib[k] >> 4) & 15, n2 = (nib[k] >> 8) & 15, n3 = (nib[k] >> 12) & 15;
        float4 rowv = make_float4((float)n0, (float)n1, (float)n2, (float)n3);
        *(((float4*)(out_sel + (size_t)(q0 + k) * N_L)) + lane) = rowv;
        float tm = 0.0f;
        if (n0) tm += (float)n0 * logf(P[k].x) - lgfact(n0);
        if (n1) tm += (float)n1 * logf(P[k].y) - lgfact(n1);
        if (n2) tm += (float)n2 * logf(P[k].z) - lgfact(n2);
        if (n3) tm += (float)n3 * logf(P[k].w) - lgfact(n3);
        term[k] = tm;
    }
    #pragma unroll
    for (int o = 32; o; o >>= 1)
        #pragma unroll
        for (int k = 0; k < 8; ++k) term[k] += __shfl_xor(term[k], o);

    if (lane < 8) {
        float rr = term[0];
        int Aa = Aq[0];
        #pragma unroll
        for (int k = 1; k < 8; ++k) {
            if (lane == k) { rr = term[k]; Aa = Aq[k]; }
        }
        out_lp[q0 + lane] = lgfact(Aa) + rr;
    }
}

extern "C" void kernel_launch(void* const* d_in, const int* in_sizes, int n_in,
                              void* d_out, int out_size, void* d_ws, size_t ws_size,
                              hipStream_t stream) {
    const float* llms      = (const float*)d_in[0];
    const float* contexts  = (const float*)d_in[1];
    const int*   agent_i   = (const int*)  d_in[2];
    // d_in[3] agent_num_float unused (int version + table)
    const float* fc1_w  = (const float*)d_in[4];  const float* fc1_b  = (const float*)d_in[5];
    const float* fc21_w = (const float*)d_in[6];  const float* fc21_b = (const float*)d_in[7];
    const float* fc22_w = (const float*)d_in[8];  const float* fc22_b = (const float*)d_in[9];
    const float* fc3_w  = (const float*)d_in[10]; const float* fc3_b  = (const float*)d_in[11];
    const float* fc4_w  = (const float*)d_in[12]; const float* fc4_b  = (const float*)d_in[13];
    const float* ctx_w  = (const float*)d_in[14]; const float* ctx_b  = (const float*)d_in[15];
    const float* noise  = (const float*)d_in[16]; const float* rand_u = (const float*)d_in[17];

    float* out      = (float*)d_out;
    float* out_sel  = out;                          // [65536][256]
    float* out_lp   = out + (size_t)N_Q * N_L;      // [65536]
    float* out_loss = out_lp + N_Q;                 // [1]

    float* emb      = (float*)d_ws;                 // [256][64]
    float* mse_row  = emb + N_L * HDIM;             // [256]
    float* kld_row  = mse_row + N_L;                // [256]

    ctx_kernel<<<2048, 512, 0, stream>>>(contexts, ctx_w, ctx_b, out_sel);
    vae_kernel<<<N_L, 64, 0, stream>>>(llms, fc1_w, fc1_b, fc21_w, fc21_b, fc22_w, fc22_b,
                                       fc3_w, fc3_b, fc4_w, fc4_b, noise,
                                       emb, mse_row, kld_row);
    loss_kernel<<<1, 256, 0, stream>>>(mse_row, kld_row, out_loss);
    route_kernel<<<2048, 256, 0, stream>>>(emb, agent_i, rand_u, out_sel, out_lp);
}